// Round 2
// baseline (483.974 us; speedup 1.0000x reference)
//
#include <hip/hip_runtime.h>
#include <hip/hip_bf16.h>

// Problem constants (R=4096, S=128, V=3, F=35)
#define NPTS      524288            // R*S
#define OUT2_BASE 4718592           // NPTS*9  (rgb_in elements)
#define NTILES    32768             // NPTS/16
#define NBLK      2048              // persistent blocks (8/CU)
#define TPB       16                // tiles per block (NTILES/NBLK, exact)

using bf16x8 = __attribute__((ext_vector_type(8))) short;   // MFMA A/B frag
using f32x4  = __attribute__((ext_vector_type(4))) float;   // MFMA C/D frag

// Weight workspace (ushort/bf16 in d_ws), [N][K] row-major, K padded, pads ZEROED:
//   WG [64][96]  @ 0      = bw1 mean part at cols 0..34, VAR part at cols 40..74
//                           (cols 35..39, 75..95 = 0) -- matches Xg LDS layout below
//   WF [64][72]  @ 6144   = bw1[:, 70:105](view part),  cols 35..71 = 0
//   W2 [32][72]  @ 10752  = bw2,  cols 64..71 = 0
//   V1 [32][40]  @ 13056  = vw1/3 (x/num_views folded), cols 32..39 = 0
//   V2 [32][40]  @ 14336  = vw2,  cols 32..39 = 0
//   R1 [32][104] @ 15616  = rw1,  cols 96..103 = 0
//   R2 [16][40]  @ 18944  = rw2,  cols 32..39 = 0

__device__ __forceinline__ ushort f2bf(float f) {
    union { float f; unsigned u; } v; v.f = f;
    unsigned u = v.u;
    unsigned r = u + 0x7fffu + ((u >> 16) & 1u);   // RTNE
    return (ushort)(r >> 16);
}
__device__ __forceinline__ uint pack2(float a, float b) {   // lo=bf16(a), hi=bf16(b)
    union { __hip_bfloat162 h; uint u; } cv;
    cv.h = __float22bfloat162_rn(make_float2(a, b));
    return cv.u;
}
__device__ __forceinline__ float eluf(float x) {
    return fmaxf(x, 0.f) + __expf(fminf(x, 0.f)) - 1.f;
}
__device__ __forceinline__ float sigm(float x) { return 1.f / (1.f + __expf(-x)); }

// unaligned-safe 8-float load (feat rows are 105 floats -> only 4B-aligned)
__device__ __forceinline__ void load8(const float* __restrict__ p, float* d) {
    __builtin_memcpy(d, p, 16);
    __builtin_memcpy(d + 4, p + 4, 16);
}

__global__ void prep_k(const float* __restrict__ bw1, const float* __restrict__ bw2,
                       const float* __restrict__ vw1, const float* __restrict__ vw2,
                       const float* __restrict__ rw1, const float* __restrict__ rw2,
                       ushort* __restrict__ w)
{
    int i = blockIdx.x * 256 + threadIdx.x;
    if (i < 6144) {                                   // WG [64][96] mean@0..34, var@40..74
        int n = i / 96, k = i % 96;
        float val = 0.f;
        if (k < 35)                 val = bw1[n * 105 + k];             // mean weights
        else if (k >= 40 && k < 75) val = bw1[n * 105 + 35 + (k - 40)]; // var weights
        w[i] = f2bf(val);
    } else if (i < 10752) {                           // WF [64][72]
        int t = i - 6144, n = t / 72, k = t % 72;
        w[i] = f2bf(k < 35 ? bw1[n * 105 + 70 + k] : 0.f);
    } else if (i < 13056) {                           // W2 [32][72]
        int t = i - 10752, n = t / 72, k = t % 72;
        w[i] = f2bf(k < 64 ? bw2[n * 64 + k] : 0.f);
    } else if (i < 14336) {                           // V1 [32][40] (/3 folded)
        int t = i - 13056, n = t / 40, k = t % 40;
        w[i] = f2bf(k < 32 ? vw1[n * 32 + k] * (1.f / 3.f) : 0.f);
    } else if (i < 15616) {                           // V2 [32][40]
        int t = i - 14336, n = t / 40, k = t % 40;
        w[i] = f2bf(k < 32 ? vw2[n * 32 + k] : 0.f);
    } else if (i < 18944) {                           // R1 [32][104]
        int t = i - 15616, n = t / 104, k = t % 104;
        w[i] = f2bf(k < 96 ? rw1[n * 96 + k] : 0.f);
    } else if (i < 19584) {                           // R2 [16][40]
        int t = i - 18944, n = t / 40, k = t % 40;
        w[i] = f2bf(k < 32 ? rw2[n * 32 + k] : 0.f);
    }
}

// PERSISTENT kernel: 2048 blocks x 16 tiles each. 2 waves/block, 16 pts/tile.
// All loop-invariant state hoisted: biases, small weight frags (36 VGPR reg-cache),
// index math (divisions), base pointers, pad zero-fill (once; pads only need
// FINITE values vs zero weight cols -- per-iteration clobbers write finite bf16).
// LDS timeline-aliased (17.2 KB -> 9-block LDS cap; 8 blocks resident):
//   shA 6912 B: h1[48][72] -> t1[48][72] -> r2b fp32[16][20]
//   shB 3328 B: Xg[16][96] -> x2[16][104]
//   shC 6912 B: Xf[48][72] -> h2[48][72] -> r1[16][40]
// 7 barriers per tile (minimal chain; see R0/R1 lifetime analysis).
__global__ __launch_bounds__(128, 4) void mlp_k(
    const float* __restrict__ feat, const ushort* __restrict__ w,
    const float* __restrict__ bb1, const float* __restrict__ bb2,
    const float* __restrict__ vb1, const float* __restrict__ vb2,
    const float* __restrict__ rb1, const float* __restrict__ rb2,
    const float* __restrict__ rw3, const float* __restrict__ rb3,
    float* __restrict__ out)
{
    __shared__ __align__(16) ushort shA[3456];
    __shared__ __align__(16) ushort shB[1664];
    __shared__ __align__(16) ushort shC[3456];

    const int tid  = threadIdx.x;
    const int wv   = tid >> 6;          // wave id 0/1
    const int lane = tid & 63;
    const int n16  = lane & 15;
    const int quad = lane >> 4;

    const ushort* WG = w;
    const ushort* WF = w + 6144;
    const ushort* W2 = w + 10752;
    const ushort* V1 = w + 13056;
    const ushort* V2 = w + 14336;
    const ushort* R1 = w + 15616;
    const ushort* R2 = w + 18944;

    // ---- hoisted: per-lane biases ----
    float bb1v[2];
#pragma unroll
    for (int ntl = 0; ntl < 2; ++ntl) bb1v[ntl] = bb1[(wv * 2 + ntl) * 16 + n16];
    const float bb2v = bb2[wv * 16 + n16];
    const float vb1v = vb1[wv * 16 + n16];
    const float vb2v = vb2[wv * 16 + n16];
    const float rb1v = rb1[wv * 16 + n16];
    const float rb2v = rb2[n16];

    // ---- hoisted: register-cached small weight frags (9 frags = 36 VGPR) ----
    bf16x8 WFf[2][2], W2f[2];
#pragma unroll
    for (int ks = 0; ks < 2; ++ks) {
#pragma unroll
        for (int ntl = 0; ntl < 2; ++ntl)
            WFf[ks][ntl] = *(const bf16x8*)(WF + ((wv * 2 + ntl) * 16 + n16) * 72 + ks * 32 + quad * 8);
        W2f[ks] = *(const bf16x8*)(W2 + (wv * 16 + n16) * 72 + ks * 32 + quad * 8);
    }
    const bf16x8 V1f = *(const bf16x8*)(V1 + (wv * 16 + n16) * 40 + quad * 8);
    const bf16x8 V2f = *(const bf16x8*)(V2 + (wv * 16 + n16) * 40 + quad * 8);
    const bf16x8 R2f = *(const bf16x8*)(R2 + n16 * 40 + quad * 8);
    // WG / R1 stay as hoisted-pointer global loads (VGPR budget)
    const ushort* WGp[2] = { WG + ((wv * 2 + 0) * 16 + n16) * 96 + quad * 8,
                             WG + ((wv * 2 + 1) * 16 + n16) * 96 + quad * 8 };
    const ushort* R1p    = R1 + (wv * 16 + n16) * 104 + quad * 8;

    // ---- hoisted: rgb-copy indices (i = tid, and tid+128 for tid<16) ----
    const int c_p = tid / 9, c_r = tid - c_p * 9;
    const int c_v = c_r / 3, c_c = c_r - c_v * 3;
    const int cp_in0 = c_p * 105 + c_v * 35 + c_c;
    const int i2 = tid + 128;
    const int d_p = i2 / 9, d_r = i2 - d_p * 9;
    const int d_v = d_r / 3, d_c = d_r - d_v * 3;
    const int cp_in1 = d_p * 105 + d_v * 35 + d_c;

    // ---- hoisted: build indices + LDS store pointers (tid<80) ----
    const int  bp   = tid / 5;
    const int  k8   = (tid - bp * 5) * 8;
    const bool bthr = tid < 80;
    const bool gthr = bthr && (k8 == 32) && (bp == 15) && (blockIdx.x == NBLK - 1);
    ushort* const stXf0 = shC + bp * 72 + k8;
    ushort* const stXf1 = shC + (16 + bp) * 72 + k8;
    ushort* const stXf2 = shC + (32 + bp) * 72 + k8;
    ushort* const stXg0 = shB + bp * 96 + k8;
    ushort* const stXg1 = shB + bp * 96 + 40 + k8;

    // ---- hoisted: final-phase constants (tid<48) ----
    const bool fthr = tid < 48;
    const int  fp = tid / 3, fc = tid - fp * 3;
    float4 q0 = {0,0,0,0}, q1 = q0, q2 = q0, q3 = q0;
    float  rb3c = 0.f;
    if (fthr) {
        const float4* w3 = (const float4*)(rw3 + fc * 16);
        q0 = w3[0]; q1 = w3[1]; q2 = w3[2]; q3 = w3[3];
        rb3c = rb3[fc];
    }
    const float* const r2row = (const float*)shA + fp * 20;

    // ---- once-per-block: pad zero-fill (finiteness only; see header comment) ----
    {
        const uint4 z = make_uint4(0u, 0u, 0u, 0u);
        uint4* zc = (uint4*)shC;                      // Xf pad cols 40..63, rows 0..47
        for (int i = tid; i < 144; i += 128) {
            int r = i / 3, c = i - r * 3;
            zc[r * 9 + 5 + c] = z;
        }
        if (tid < 32) {                               // Xg pad cols 80..95, rows 0..15
            uint4* zb = (uint4*)shB;
            int r = tid >> 1, c = tid & 1;
            zb[r * 12 + 10 + c] = z;
        }
    }

    // ---- per-block base pointers (advanced each iteration) ----
    const long long pbase0 = (long long)blockIdx.x * (TPB * 16);
    const float* fin  = feat + pbase0 * 105;
    const float* brow = feat + (pbase0 + bp) * 105;
    float*       orgb = out + pbase0 * 9;
    float*       o2   = out + OUT2_BASE + pbase0 * 3;

    const f32x4 Z = {0.f, 0.f, 0.f, 0.f};

#pragma unroll 1
    for (int it = 0; it < TPB; ++it) {
        // ---- phase A: rgb_in passthrough + build Xg/Xf from global ----
        orgb[tid] = fin[cp_in0];
        if (tid < 16) orgb[i2] = fin[cp_in1];
        if (bthr) {
            float X0[8], X1[8], X2[8];
            load8(brow + k8,      X0);   // view 0 (tail overread: finite, zero-weight)
            load8(brow + 35 + k8, X1);   // view 1
            if (gthr && it == TPB - 1) { // very last point of the whole tensor
                X2[0] = brow[102]; X2[1] = brow[103]; X2[2] = brow[104];
                X2[3] = 0.f; X2[4] = 0.f; X2[5] = 0.f; X2[6] = 0.f; X2[7] = 0.f;
            } else {
                load8(brow + 70 + k8, X2);   // view 2
            }
            float M[8], VV[8];
#pragma unroll
            for (int j = 0; j < 8; ++j) {
                float a = X0[j], b = X1[j], c = X2[j];
                float m  = (a + b + c) * (1.f / 3.f);
                float da = a - m, db = b - m, dc = c - m;
                M[j]  = m;
                VV[j] = (da * da + db * db + dc * dc) * (1.f / 3.f);
            }
            *(uint4*)stXf0 = make_uint4(pack2(X0[0], X0[1]), pack2(X0[2], X0[3]),
                                        pack2(X0[4], X0[5]), pack2(X0[6], X0[7]));
            *(uint4*)stXf1 = make_uint4(pack2(X1[0], X1[1]), pack2(X1[2], X1[3]),
                                        pack2(X1[4], X1[5]), pack2(X1[6], X1[7]));
            *(uint4*)stXf2 = make_uint4(pack2(X2[0], X2[1]), pack2(X2[2], X2[3]),
                                        pack2(X2[4], X2[5]), pack2(X2[6], X2[7]));
            *(uint4*)stXg0 = make_uint4(pack2(M[0], M[1]), pack2(M[2], M[3]),
                                        pack2(M[4], M[5]), pack2(M[6], M[7]));
            *(uint4*)stXg1 = make_uint4(pack2(VV[0], VV[1]), pack2(VV[2], VV[3]),
                                        pack2(VV[4], VV[5]), pack2(VV[6], VV[7]));
        }
        __syncthreads();                              // BAR1: Xg/Xf ready

        // ---- layer 1 ----
        f32x4 Cg[2]    = {Z, Z};
        f32x4 Cf[3][2] = {{Z, Z}, {Z, Z}, {Z, Z}};
#pragma unroll
        for (int ks = 0; ks < 3; ++ks) {              // K=96 : [mean|var]
            bf16x8 a = *(const bf16x8*)(shB + n16 * 96 + ks * 32 + quad * 8);
#pragma unroll
            for (int ntl = 0; ntl < 2; ++ntl) {
                bf16x8 b = *(const bf16x8*)(WGp[ntl] + ks * 32);
                Cg[ntl] = __builtin_amdgcn_mfma_f32_16x16x32_bf16(a, b, Cg[ntl], 0, 0, 0);
            }
        }
#pragma unroll
        for (int ks = 0; ks < 2; ++ks) {              // K=64 : view feat
            bf16x8 a0 = *(const bf16x8*)(shC + (0 * 16 + n16) * 72 + ks * 32 + quad * 8);
            bf16x8 a1 = *(const bf16x8*)(shC + (1 * 16 + n16) * 72 + ks * 32 + quad * 8);
            bf16x8 a2 = *(const bf16x8*)(shC + (2 * 16 + n16) * 72 + ks * 32 + quad * 8);
#pragma unroll
            for (int ntl = 0; ntl < 2; ++ntl) {
                Cf[0][ntl] = __builtin_amdgcn_mfma_f32_16x16x32_bf16(a0, WFf[ks][ntl], Cf[0][ntl], 0, 0, 0);
                Cf[1][ntl] = __builtin_amdgcn_mfma_f32_16x16x32_bf16(a1, WFf[ks][ntl], Cf[1][ntl], 0, 0, 0);
                Cf[2][ntl] = __builtin_amdgcn_mfma_f32_16x16x32_bf16(a2, WFf[ks][ntl], Cf[2][ntl], 0, 0, 0);
            }
        }
        // h1 = elu(Cf + Cg + bb1) -> shA [48][72] (shA has no live readers here)
#pragma unroll
        for (int mt = 0; mt < 3; ++mt)
#pragma unroll
            for (int ntl = 0; ntl < 2; ++ntl) {
                float e0 = eluf(Cf[mt][ntl][0] + Cg[ntl][0] + bb1v[ntl]);
                float e1 = eluf(Cf[mt][ntl][1] + Cg[ntl][1] + bb1v[ntl]);
                float e2 = eluf(Cf[mt][ntl][2] + Cg[ntl][2] + bb1v[ntl]);
                float e3 = eluf(Cf[mt][ntl][3] + Cg[ntl][3] + bb1v[ntl]);
                int col = (wv * 2 + ntl) * 16 + n16;
                int r0  = (mt * 16 + quad * 4) * 72 + col;
                uint u01 = pack2(e0, e1), u23 = pack2(e2, e3);
                shA[r0]       = (ushort)u01;
                shA[r0 + 72]  = (ushort)(u01 >> 16);
                shA[r0 + 144] = (ushort)u23;
                shA[r0 + 216] = (ushort)(u23 >> 16);
            }
        __syncthreads();                              // BAR2: h1 ready (Xf readers drained)

        // ---- layer 2 ----
        f32x4 C2[3] = {Z, Z, Z};
#pragma unroll
        for (int ks = 0; ks < 2; ++ks) {
            bf16x8 a0 = *(const bf16x8*)(shA + (0 * 16 + n16) * 72 + ks * 32 + quad * 8);
            bf16x8 a1 = *(const bf16x8*)(shA + (1 * 16 + n16) * 72 + ks * 32 + quad * 8);
            bf16x8 a2 = *(const bf16x8*)(shA + (2 * 16 + n16) * 72 + ks * 32 + quad * 8);
            C2[0] = __builtin_amdgcn_mfma_f32_16x16x32_bf16(a0, W2f[ks], C2[0], 0, 0, 0);
            C2[1] = __builtin_amdgcn_mfma_f32_16x16x32_bf16(a1, W2f[ks], C2[1], 0, 0, 0);
            C2[2] = __builtin_amdgcn_mfma_f32_16x16x32_bf16(a2, W2f[ks], C2[2], 0, 0, 0);
        }
        // h2 -> shC (its last readers drained at BAR2)
        float h2r[3][4];
#pragma unroll
        for (int mt = 0; mt < 3; ++mt) {
            float e0 = eluf(C2[mt][0] + bb2v);
            float e1 = eluf(C2[mt][1] + bb2v);
            float e2 = eluf(C2[mt][2] + bb2v);
            float e3 = eluf(C2[mt][3] + bb2v);
            h2r[mt][0] = e0; h2r[mt][1] = e1; h2r[mt][2] = e2; h2r[mt][3] = e3;
            int r0 = (mt * 16 + quad * 4) * 72 + wv * 16 + n16;
            uint u01 = pack2(e0, e1), u23 = pack2(e2, e3);
            shC[r0]       = (ushort)u01;
            shC[r0 + 72]  = (ushort)(u01 >> 16);
            shC[r0 + 144] = (ushort)u23;
            shC[r0 + 216] = (ushort)(u23 >> 16);
        }
        __syncthreads();                              // BAR3: h2 ready

        // ---- vis layer 1 (K=32) ----
        f32x4 T1[3] = {Z, Z, Z};
        {
            bf16x8 a0 = *(const bf16x8*)(shC + (0 * 16 + n16) * 72 + quad * 8);
            bf16x8 a1 = *(const bf16x8*)(shC + (1 * 16 + n16) * 72 + quad * 8);
            bf16x8 a2 = *(const bf16x8*)(shC + (2 * 16 + n16) * 72 + quad * 8);
            T1[0] = __builtin_amdgcn_mfma_f32_16x16x32_bf16(a0, V1f, T1[0], 0, 0, 0);
            T1[1] = __builtin_amdgcn_mfma_f32_16x16x32_bf16(a1, V1f, T1[1], 0, 0, 0);
            T1[2] = __builtin_amdgcn_mfma_f32_16x16x32_bf16(a2, V1f, T1[2], 0, 0, 0);
        }
        // t1 -> shA (h1 readers drained at BAR3)
#pragma unroll
        for (int mt = 0; mt < 3; ++mt) {
            float e0 = eluf(T1[mt][0] + vb1v);
            float e1 = eluf(T1[mt][1] + vb1v);
            float e2 = eluf(T1[mt][2] + vb1v);
            float e3 = eluf(T1[mt][3] + vb1v);
            int r0 = (mt * 16 + quad * 4) * 72 + wv * 16 + n16;
            uint u01 = pack2(e0, e1), u23 = pack2(e2, e3);
            shA[r0]       = (ushort)u01;
            shA[r0 + 72]  = (ushort)(u01 >> 16);
            shA[r0 + 144] = (ushort)u23;
            shA[r0 + 216] = (ushort)(u23 >> 16);
        }
        __syncthreads();                              // BAR4: t1 ready

        // ---- vis layer 2 + residual -> x2 (shB [16][104]) ----
        f32x4 T2[3] = {Z, Z, Z};
        {
            bf16x8 a0 = *(const bf16x8*)(shA + (0 * 16 + n16) * 72 + quad * 8);
            bf16x8 a1 = *(const bf16x8*)(shA + (1 * 16 + n16) * 72 + quad * 8);
            bf16x8 a2 = *(const bf16x8*)(shA + (2 * 16 + n16) * 72 + quad * 8);
            T2[0] = __builtin_amdgcn_mfma_f32_16x16x32_bf16(a0, V2f, T2[0], 0, 0, 0);
            T2[1] = __builtin_amdgcn_mfma_f32_16x16x32_bf16(a1, V2f, T2[1], 0, 0, 0);
            T2[2] = __builtin_amdgcn_mfma_f32_16x16x32_bf16(a2, V2f, T2[2], 0, 0, 0);
        }
        // x2 -> shB (Xg readers drained at BAR2)
#pragma unroll
        for (int mt = 0; mt < 3; ++mt) {
            float x0  = h2r[mt][0] + eluf(T2[mt][0] + vb2v);
            float x1  = h2r[mt][1] + eluf(T2[mt][1] + vb2v);
            float x2v = h2r[mt][2] + eluf(T2[mt][2] + vb2v);
            float x3  = h2r[mt][3] + eluf(T2[mt][3] + vb2v);
            int col = mt * 32 + wv * 16 + n16;        // v*32 + c concat layout
            int r0  = (quad * 4) * 104 + col;
            uint u01 = pack2(x0, x1), u23 = pack2(x2v, x3);
            shB[r0]       = (ushort)u01;
            shB[r0 + 104] = (ushort)(u01 >> 16);
            shB[r0 + 208] = (ushort)u23;
            shB[r0 + 312] = (ushort)(u23 >> 16);
        }
        __syncthreads();                              // BAR5: x2 ready

        // ---- r1 = elu(x2 @ R1^T + rb1) ----
        f32x4 CR = Z;
#pragma unroll
        for (int ks = 0; ks < 3; ++ks) {              // K=96
            bf16x8 a = *(const bf16x8*)(shB + n16 * 104 + ks * 32 + quad * 8);
            bf16x8 b = *(const bf16x8*)(R1p + ks * 32);
            CR = __builtin_amdgcn_mfma_f32_16x16x32_bf16(a, b, CR, 0, 0, 0);
        }
        // r1 -> shC [16][40] (h2 readers drained at BAR4; clobbered Xf pads stay finite)
        {
            float e0 = eluf(CR[0] + rb1v);
            float e1 = eluf(CR[1] + rb1v);
            float e2 = eluf(CR[2] + rb1v);
            float e3 = eluf(CR[3] + rb1v);
            int r0 = (quad * 4) * 40 + wv * 16 + n16;
            uint u01 = pack2(e0, e1), u23 = pack2(e2, e3);
            shC[r0]       = (ushort)u01;
            shC[r0 + 40]  = (ushort)(u01 >> 16);
            shC[r0 + 80]  = (ushort)u23;
            shC[r0 + 120] = (ushort)(u23 >> 16);
        }
        __syncthreads();                              // BAR6: r1 ready

        // ---- r2 = elu(r1 @ R2^T + rb2) -> fp32 shA [16][20] ----
        f32x4 C3 = Z;
        {
            bf16x8 a = *(const bf16x8*)(shC + n16 * 40 + quad * 8);
            C3 = __builtin_amdgcn_mfma_f32_16x16x32_bf16(a, R2f, C3, 0, 0, 0);
        }
        // r2 -> shA fp32 (t1 readers drained at BAR5)
        {
            float* r2b = (float*)shA;
#pragma unroll
            for (int rr = 0; rr < 2; ++rr) {          // wave wv writes r = 2wv+rr
                int r = 2 * wv + rr;
                r2b[(quad * 4 + r) * 20 + n16] = eluf(C3[r] + rb2v);
            }
        }
        __syncthreads();                              // BAR7: r2 ready

        // ---- final 16 -> 3 + sigmoid, coalesced store ----
        // (reads shA only; next iteration's shA writes are behind BAR1+BAR2)
        if (fthr) {
            const float4* rr = (const float4*)r2row;
            float4 a0 = rr[0], a1 = rr[1], a2 = rr[2], a3 = rr[3];
            float s = rb3c;
            s += a0.x * q0.x + a0.y * q0.y + a0.z * q0.z + a0.w * q0.w;
            s += a1.x * q1.x + a1.y * q1.y + a1.z * q1.z + a1.w * q1.w;
            s += a2.x * q2.x + a2.y * q2.y + a2.z * q2.z + a2.w * q2.w;
            s += a3.x * q3.x + a3.y * q3.y + a3.z * q3.z + a3.w * q3.w;
            o2[tid] = sigm(s);
        }

        // advance per-tile pointers
        fin  += 16 * 105;
        brow += 16 * 105;
        orgb += 144;
        o2   += 48;
    }
}

extern "C" void kernel_launch(void* const* d_in, const int* in_sizes, int n_in,
                              void* d_out, int out_size, void* d_ws, size_t ws_size,
                              hipStream_t stream) {
    const float* feat = (const float*)d_in[0];
    const float* bw1  = (const float*)d_in[1];
    const float* bb1  = (const float*)d_in[2];
    const float* bw2  = (const float*)d_in[3];
    const float* bb2  = (const float*)d_in[4];
    const float* vw1  = (const float*)d_in[5];
    const float* vb1  = (const float*)d_in[6];
    const float* vw2  = (const float*)d_in[7];
    const float* vb2  = (const float*)d_in[8];
    const float* rw1  = (const float*)d_in[9];
    const float* rb1  = (const float*)d_in[10];
    const float* rw2  = (const float*)d_in[11];
    const float* rb2  = (const float*)d_in[12];
    const float* rw3  = (const float*)d_in[13];
    const float* rb3  = (const float*)d_in[14];
    ushort* w  = (ushort*)d_ws;
    float* out = (float*)d_out;

    hipLaunchKernelGGL(prep_k, dim3(77), dim3(256), 0, stream,
                       bw1, bw2, vw1, vw2, rw1, rw2, w);
    hipLaunchKernelGGL(mlp_k, dim3(NBLK), dim3(128), 0, stream,
                       feat, w, bb1, bb2, vb1, vb2, rb1, rb2, rw3, rb3, out);
}

// Round 3
// 475.642 us; speedup vs baseline: 1.0175x; 1.0175x over previous
//
#include <hip/hip_runtime.h>
#include <hip/hip_bf16.h>

// Problem constants (R=4096, S=128, V=3, F=35)
#define NPTS      524288            // R*S
#define OUT2_BASE 4718592           // NPTS*9  (rgb_in elements)
#define NTILES    32768             // NPTS/16
#define NBLK      2048              // persistent blocks (8/CU)
#define TPB       16                // tiles per block (NTILES/NBLK, exact)

using bf16x8 = __attribute__((ext_vector_type(8))) short;   // MFMA A/B frag
using f32x4  = __attribute__((ext_vector_type(4))) float;   // MFMA C/D frag

// Weight workspace (ushort/bf16 in d_ws), [N][K] row-major, K padded, pads ZEROED:
//   WG [64][96]  @ 0      = bw1 mean part at cols 0..34, VAR part at cols 40..74
//                           (cols 35..39, 75..95 = 0) -- matches Xg LDS layout below
//   WF [64][72]  @ 6144   = bw1[:, 70:105](view part),  cols 35..71 = 0
//   W2 [32][72]  @ 10752  = bw2,  cols 64..71 = 0
//   V1 [32][40]  @ 13056  = vw1/3 (x/num_views folded), cols 32..39 = 0
//   V2 [32][40]  @ 14336  = vw2,  cols 32..39 = 0
//   R1 [32][104] @ 15616  = rw1,  cols 96..103 = 0
//   R2 [16][40]  @ 18944  = rw2,  cols 32..39 = 0

__device__ __forceinline__ ushort f2bf(float f) {
    union { float f; unsigned u; } v; v.f = f;
    unsigned u = v.u;
    unsigned r = u + 0x7fffu + ((u >> 16) & 1u);   // RTNE
    return (ushort)(r >> 16);
}
__device__ __forceinline__ uint pack2(float a, float b) {   // lo=bf16(a), hi=bf16(b)
    union { __hip_bfloat162 h; uint u; } cv;
    cv.h = __float22bfloat162_rn(make_float2(a, b));
    return cv.u;
}
__device__ __forceinline__ float eluf(float x) {
    return fmaxf(x, 0.f) + __expf(fminf(x, 0.f)) - 1.f;
}
__device__ __forceinline__ float sigm(float x) { return 1.f / (1.f + __expf(-x)); }

// unaligned-safe 8-float load (feat rows are 105 floats -> only 4B-aligned)
__device__ __forceinline__ void load8(const float* __restrict__ p, float* d) {
    __builtin_memcpy(d, p, 16);
    __builtin_memcpy(d + 4, p + 4, 16);
}

__global__ void prep_k(const float* __restrict__ bw1, const float* __restrict__ bw2,
                       const float* __restrict__ vw1, const float* __restrict__ vw2,
                       const float* __restrict__ rw1, const float* __restrict__ rw2,
                       ushort* __restrict__ w)
{
    int i = blockIdx.x * 256 + threadIdx.x;
    if (i < 6144) {                                   // WG [64][96] mean@0..34, var@40..74
        int n = i / 96, k = i % 96;
        float val = 0.f;
        if (k < 35)                 val = bw1[n * 105 + k];             // mean weights
        else if (k >= 40 && k < 75) val = bw1[n * 105 + 35 + (k - 40)]; // var weights
        w[i] = f2bf(val);
    } else if (i < 10752) {                           // WF [64][72]
        int t = i - 6144, n = t / 72, k = t % 72;
        w[i] = f2bf(k < 35 ? bw1[n * 105 + 70 + k] : 0.f);
    } else if (i < 13056) {                           // W2 [32][72]
        int t = i - 10752, n = t / 72, k = t % 72;
        w[i] = f2bf(k < 64 ? bw2[n * 64 + k] : 0.f);
    } else if (i < 14336) {                           // V1 [32][40] (/3 folded)
        int t = i - 13056, n = t / 40, k = t % 40;
        w[i] = f2bf(k < 32 ? vw1[n * 32 + k] * (1.f / 3.f) : 0.f);
    } else if (i < 15616) {                           // V2 [32][40]
        int t = i - 14336, n = t / 40, k = t % 40;
        w[i] = f2bf(k < 32 ? vw2[n * 32 + k] : 0.f);
    } else if (i < 18944) {                           // R1 [32][104]
        int t = i - 15616, n = t / 104, k = t % 104;
        w[i] = f2bf(k < 96 ? rw1[n * 96 + k] : 0.f);
    } else if (i < 19584) {                           // R2 [16][40]
        int t = i - 18944, n = t / 40, k = t % 40;
        w[i] = f2bf(k < 32 ? rw2[n * 32 + k] : 0.f);
    }
}

// PERSISTENT kernel, GRID-STRIDE tile order: block b -> tiles b, b+2048, b+4096...
// At iteration it, the device's active tiles are exactly [it*2048,(it+1)*2048) --
// a contiguous ~14 MB sliding address window (same global order as a plain
// 32768-block dispatch). R2's chunked order (block b -> tiles 16b..16b+15)
// scattered 2048 pointers across the whole 220-MB input -> L3 thrash,
// FETCH_SIZE 108->433 MB, +61 us of HBM time. Grid-stride keeps the L3-friendly
// sweep while retaining all per-block hoisting (biases, weight frags, index
// divisions, pad zero-fill, kernel setup amortized over 16 tiles).
// LDS timeline-aliased (17.2 KB):
//   shA 6912 B: h1[48][72] -> t1[48][72] -> r2b fp32[16][20]
//   shB 3328 B: Xg[16][96] -> x2[16][104]
//   shC 6912 B: Xf[48][72] -> h2[48][72] -> r1[16][40]
// 7 barriers per tile (minimal chain; see R0/R1 lifetime analysis).
__global__ __launch_bounds__(128, 4) void mlp_k(
    const float* __restrict__ feat, const ushort* __restrict__ w,
    const float* __restrict__ bb1, const float* __restrict__ bb2,
    const float* __restrict__ vb1, const float* __restrict__ vb2,
    const float* __restrict__ rb1, const float* __restrict__ rb2,
    const float* __restrict__ rw3, const float* __restrict__ rb3,
    float* __restrict__ out)
{
    __shared__ __align__(16) ushort shA[3456];
    __shared__ __align__(16) ushort shB[1664];
    __shared__ __align__(16) ushort shC[3456];

    const int tid  = threadIdx.x;
    const int wv   = tid >> 6;          // wave id 0/1
    const int lane = tid & 63;
    const int n16  = lane & 15;
    const int quad = lane >> 4;

    const ushort* WG = w;
    const ushort* WF = w + 6144;
    const ushort* W2 = w + 10752;
    const ushort* V1 = w + 13056;
    const ushort* V2 = w + 14336;
    const ushort* R1 = w + 15616;
    const ushort* R2 = w + 18944;

    // ---- hoisted: per-lane biases ----
    float bb1v[2];
#pragma unroll
    for (int ntl = 0; ntl < 2; ++ntl) bb1v[ntl] = bb1[(wv * 2 + ntl) * 16 + n16];
    const float bb2v = bb2[wv * 16 + n16];
    const float vb1v = vb1[wv * 16 + n16];
    const float vb2v = vb2[wv * 16 + n16];
    const float rb1v = rb1[wv * 16 + n16];
    const float rb2v = rb2[n16];

    // ---- hoisted: register-cached small weight frags (9 frags = 36 VGPR) ----
    bf16x8 WFf[2][2], W2f[2];
#pragma unroll
    for (int ks = 0; ks < 2; ++ks) {
#pragma unroll
        for (int ntl = 0; ntl < 2; ++ntl)
            WFf[ks][ntl] = *(const bf16x8*)(WF + ((wv * 2 + ntl) * 16 + n16) * 72 + ks * 32 + quad * 8);
        W2f[ks] = *(const bf16x8*)(W2 + (wv * 16 + n16) * 72 + ks * 32 + quad * 8);
    }
    const bf16x8 V1f = *(const bf16x8*)(V1 + (wv * 16 + n16) * 40 + quad * 8);
    const bf16x8 V2f = *(const bf16x8*)(V2 + (wv * 16 + n16) * 40 + quad * 8);
    const bf16x8 R2f = *(const bf16x8*)(R2 + n16 * 40 + quad * 8);
    // WG / R1 stay as hoisted-pointer global loads (VGPR budget)
    const ushort* WGp[2] = { WG + ((wv * 2 + 0) * 16 + n16) * 96 + quad * 8,
                             WG + ((wv * 2 + 1) * 16 + n16) * 96 + quad * 8 };
    const ushort* R1p    = R1 + (wv * 16 + n16) * 104 + quad * 8;

    // ---- hoisted: rgb-copy indices (i = tid, and tid+128 for tid<16) ----
    const int c_p = tid / 9, c_r = tid - c_p * 9;
    const int c_v = c_r / 3, c_c = c_r - c_v * 3;
    const int cp_in0 = c_p * 105 + c_v * 35 + c_c;
    const int i2 = tid + 128;
    const int d_p = i2 / 9, d_r = i2 - d_p * 9;
    const int d_v = d_r / 3, d_c = d_r - d_v * 3;
    const int cp_in1 = d_p * 105 + d_v * 35 + d_c;

    // ---- hoisted: build indices + LDS store pointers (tid<80) ----
    const int  bp   = tid / 5;
    const int  k8   = (tid - bp * 5) * 8;
    const bool bthr = tid < 80;
    const bool gthr = bthr && (k8 == 32) && (bp == 15) && (blockIdx.x == NBLK - 1);
    ushort* const stXf0 = shC + bp * 72 + k8;
    ushort* const stXf1 = shC + (16 + bp) * 72 + k8;
    ushort* const stXf2 = shC + (32 + bp) * 72 + k8;
    ushort* const stXg0 = shB + bp * 96 + k8;
    ushort* const stXg1 = shB + bp * 96 + 40 + k8;

    // ---- hoisted: final-phase constants (tid<48) ----
    const bool fthr = tid < 48;
    const int  fp = tid / 3, fc = tid - fp * 3;
    float4 q0 = {0,0,0,0}, q1 = q0, q2 = q0, q3 = q0;
    float  rb3c = 0.f;
    if (fthr) {
        const float4* w3 = (const float4*)(rw3 + fc * 16);
        q0 = w3[0]; q1 = w3[1]; q2 = w3[2]; q3 = w3[3];
        rb3c = rb3[fc];
    }
    const float* const r2row = (const float*)shA + fp * 20;

    // ---- once-per-block: pad zero-fill (finiteness only; see header comment) ----
    {
        const uint4 z = make_uint4(0u, 0u, 0u, 0u);
        uint4* zc = (uint4*)shC;                      // Xf pad cols 40..63, rows 0..47
        for (int i = tid; i < 144; i += 128) {
            int r = i / 3, c = i - r * 3;
            zc[r * 9 + 5 + c] = z;
        }
        if (tid < 32) {                               // Xg pad cols 80..95, rows 0..15
            uint4* zb = (uint4*)shB;
            int r = tid >> 1, c = tid & 1;
            zb[r * 12 + 10 + c] = z;
        }
    }

    // ---- per-block base pointers: tile = blockIdx.x, advanced by NBLK tiles/iter ----
    const long long pbase0 = (long long)blockIdx.x * 16;
    const long long STRIDE = (long long)NBLK * 16;    // points per grid-stride step
    const float* fin  = feat + pbase0 * 105;
    const float* brow = feat + (pbase0 + bp) * 105;
    float*       orgb = out + pbase0 * 9;
    float*       o2   = out + OUT2_BASE + pbase0 * 3;

    const f32x4 Z = {0.f, 0.f, 0.f, 0.f};

#pragma unroll 1
    for (int it = 0; it < TPB; ++it) {
        // ---- phase A: rgb_in passthrough + build Xg/Xf from global ----
        orgb[tid] = fin[cp_in0];
        if (tid < 16) orgb[i2] = fin[cp_in1];
        if (bthr) {
            float X0[8], X1[8], X2[8];
            load8(brow + k8,      X0);   // view 0 (tail overread: finite, zero-weight)
            load8(brow + 35 + k8, X1);   // view 1
            if (gthr && it == TPB - 1) { // very last point of the whole tensor
                X2[0] = brow[102]; X2[1] = brow[103]; X2[2] = brow[104];
                X2[3] = 0.f; X2[4] = 0.f; X2[5] = 0.f; X2[6] = 0.f; X2[7] = 0.f;
            } else {
                load8(brow + 70 + k8, X2);   // view 2
            }
            float M[8], VV[8];
#pragma unroll
            for (int j = 0; j < 8; ++j) {
                float a = X0[j], b = X1[j], c = X2[j];
                float m  = (a + b + c) * (1.f / 3.f);
                float da = a - m, db = b - m, dc = c - m;
                M[j]  = m;
                VV[j] = (da * da + db * db + dc * dc) * (1.f / 3.f);
            }
            *(uint4*)stXf0 = make_uint4(pack2(X0[0], X0[1]), pack2(X0[2], X0[3]),
                                        pack2(X0[4], X0[5]), pack2(X0[6], X0[7]));
            *(uint4*)stXf1 = make_uint4(pack2(X1[0], X1[1]), pack2(X1[2], X1[3]),
                                        pack2(X1[4], X1[5]), pack2(X1[6], X1[7]));
            *(uint4*)stXf2 = make_uint4(pack2(X2[0], X2[1]), pack2(X2[2], X2[3]),
                                        pack2(X2[4], X2[5]), pack2(X2[6], X2[7]));
            *(uint4*)stXg0 = make_uint4(pack2(M[0], M[1]), pack2(M[2], M[3]),
                                        pack2(M[4], M[5]), pack2(M[6], M[7]));
            *(uint4*)stXg1 = make_uint4(pack2(VV[0], VV[1]), pack2(VV[2], VV[3]),
                                        pack2(VV[4], VV[5]), pack2(VV[6], VV[7]));
        }
        __syncthreads();                              // BAR1: Xg/Xf ready

        // ---- layer 1 ----
        f32x4 Cg[2]    = {Z, Z};
        f32x4 Cf[3][2] = {{Z, Z}, {Z, Z}, {Z, Z}};
#pragma unroll
        for (int ks = 0; ks < 3; ++ks) {              // K=96 : [mean|var]
            bf16x8 a = *(const bf16x8*)(shB + n16 * 96 + ks * 32 + quad * 8);
#pragma unroll
            for (int ntl = 0; ntl < 2; ++ntl) {
                bf16x8 b = *(const bf16x8*)(WGp[ntl] + ks * 32);
                Cg[ntl] = __builtin_amdgcn_mfma_f32_16x16x32_bf16(a, b, Cg[ntl], 0, 0, 0);
            }
        }
#pragma unroll
        for (int ks = 0; ks < 2; ++ks) {              // K=64 : view feat
            bf16x8 a0 = *(const bf16x8*)(shC + (0 * 16 + n16) * 72 + ks * 32 + quad * 8);
            bf16x8 a1 = *(const bf16x8*)(shC + (1 * 16 + n16) * 72 + ks * 32 + quad * 8);
            bf16x8 a2 = *(const bf16x8*)(shC + (2 * 16 + n16) * 72 + ks * 32 + quad * 8);
#pragma unroll
            for (int ntl = 0; ntl < 2; ++ntl) {
                Cf[0][ntl] = __builtin_amdgcn_mfma_f32_16x16x32_bf16(a0, WFf[ks][ntl], Cf[0][ntl], 0, 0, 0);
                Cf[1][ntl] = __builtin_amdgcn_mfma_f32_16x16x32_bf16(a1, WFf[ks][ntl], Cf[1][ntl], 0, 0, 0);
                Cf[2][ntl] = __builtin_amdgcn_mfma_f32_16x16x32_bf16(a2, WFf[ks][ntl], Cf[2][ntl], 0, 0, 0);
            }
        }
        // h1 = elu(Cf + Cg + bb1) -> shA [48][72] (shA has no live readers here)
#pragma unroll
        for (int mt = 0; mt < 3; ++mt)
#pragma unroll
            for (int ntl = 0; ntl < 2; ++ntl) {
                float e0 = eluf(Cf[mt][ntl][0] + Cg[ntl][0] + bb1v[ntl]);
                float e1 = eluf(Cf[mt][ntl][1] + Cg[ntl][1] + bb1v[ntl]);
                float e2 = eluf(Cf[mt][ntl][2] + Cg[ntl][2] + bb1v[ntl]);
                float e3 = eluf(Cf[mt][ntl][3] + Cg[ntl][3] + bb1v[ntl]);
                int col = (wv * 2 + ntl) * 16 + n16;
                int r0  = (mt * 16 + quad * 4) * 72 + col;
                uint u01 = pack2(e0, e1), u23 = pack2(e2, e3);
                shA[r0]       = (ushort)u01;
                shA[r0 + 72]  = (ushort)(u01 >> 16);
                shA[r0 + 144] = (ushort)u23;
                shA[r0 + 216] = (ushort)(u23 >> 16);
            }
        __syncthreads();                              // BAR2: h1 ready (Xf readers drained)

        // ---- layer 2 ----
        f32x4 C2[3] = {Z, Z, Z};
#pragma unroll
        for (int ks = 0; ks < 2; ++ks) {
            bf16x8 a0 = *(const bf16x8*)(shA + (0 * 16 + n16) * 72 + ks * 32 + quad * 8);
            bf16x8 a1 = *(const bf16x8*)(shA + (1 * 16 + n16) * 72 + ks * 32 + quad * 8);
            bf16x8 a2 = *(const bf16x8*)(shA + (2 * 16 + n16) * 72 + ks * 32 + quad * 8);
            C2[0] = __builtin_amdgcn_mfma_f32_16x16x32_bf16(a0, W2f[ks], C2[0], 0, 0, 0);
            C2[1] = __builtin_amdgcn_mfma_f32_16x16x32_bf16(a1, W2f[ks], C2[1], 0, 0, 0);
            C2[2] = __builtin_amdgcn_mfma_f32_16x16x32_bf16(a2, W2f[ks], C2[2], 0, 0, 0);
        }
        // h2 -> shC (its last readers drained at BAR2)
        float h2r[3][4];
#pragma unroll
        for (int mt = 0; mt < 3; ++mt) {
            float e0 = eluf(C2[mt][0] + bb2v);
            float e1 = eluf(C2[mt][1] + bb2v);
            float e2 = eluf(C2[mt][2] + bb2v);
            float e3 = eluf(C2[mt][3] + bb2v);
            h2r[mt][0] = e0; h2r[mt][1] = e1; h2r[mt][2] = e2; h2r[mt][3] = e3;
            int r0 = (mt * 16 + quad * 4) * 72 + wv * 16 + n16;
            uint u01 = pack2(e0, e1), u23 = pack2(e2, e3);
            shC[r0]       = (ushort)u01;
            shC[r0 + 72]  = (ushort)(u01 >> 16);
            shC[r0 + 144] = (ushort)u23;
            shC[r0 + 216] = (ushort)(u23 >> 16);
        }
        __syncthreads();                              // BAR3: h2 ready

        // ---- vis layer 1 (K=32) ----
        f32x4 T1[3] = {Z, Z, Z};
        {
            bf16x8 a0 = *(const bf16x8*)(shC + (0 * 16 + n16) * 72 + quad * 8);
            bf16x8 a1 = *(const bf16x8*)(shC + (1 * 16 + n16) * 72 + quad * 8);
            bf16x8 a2 = *(const bf16x8*)(shC + (2 * 16 + n16) * 72 + quad * 8);
            T1[0] = __builtin_amdgcn_mfma_f32_16x16x32_bf16(a0, V1f, T1[0], 0, 0, 0);
            T1[1] = __builtin_amdgcn_mfma_f32_16x16x32_bf16(a1, V1f, T1[1], 0, 0, 0);
            T1[2] = __builtin_amdgcn_mfma_f32_16x16x32_bf16(a2, V1f, T1[2], 0, 0, 0);
        }
        // t1 -> shA (h1 readers drained at BAR3)
#pragma unroll
        for (int mt = 0; mt < 3; ++mt) {
            float e0 = eluf(T1[mt][0] + vb1v);
            float e1 = eluf(T1[mt][1] + vb1v);
            float e2 = eluf(T1[mt][2] + vb1v);
            float e3 = eluf(T1[mt][3] + vb1v);
            int r0 = (mt * 16 + quad * 4) * 72 + wv * 16 + n16;
            uint u01 = pack2(e0, e1), u23 = pack2(e2, e3);
            shA[r0]       = (ushort)u01;
            shA[r0 + 72]  = (ushort)(u01 >> 16);
            shA[r0 + 144] = (ushort)u23;
            shA[r0 + 216] = (ushort)(u23 >> 16);
        }
        __syncthreads();                              // BAR4: t1 ready

        // ---- vis layer 2 + residual -> x2 (shB [16][104]) ----
        f32x4 T2[3] = {Z, Z, Z};
        {
            bf16x8 a0 = *(const bf16x8*)(shA + (0 * 16 + n16) * 72 + quad * 8);
            bf16x8 a1 = *(const bf16x8*)(shA + (1 * 16 + n16) * 72 + quad * 8);
            bf16x8 a2 = *(const bf16x8*)(shA + (2 * 16 + n16) * 72 + quad * 8);
            T2[0] = __builtin_amdgcn_mfma_f32_16x16x32_bf16(a0, V2f, T2[0], 0, 0, 0);
            T2[1] = __builtin_amdgcn_mfma_f32_16x16x32_bf16(a1, V2f, T2[1], 0, 0, 0);
            T2[2] = __builtin_amdgcn_mfma_f32_16x16x32_bf16(a2, V2f, T2[2], 0, 0, 0);
        }
        // x2 -> shB (Xg readers drained at BAR2)
#pragma unroll
        for (int mt = 0; mt < 3; ++mt) {
            float x0  = h2r[mt][0] + eluf(T2[mt][0] + vb2v);
            float x1  = h2r[mt][1] + eluf(T2[mt][1] + vb2v);
            float x2v = h2r[mt][2] + eluf(T2[mt][2] + vb2v);
            float x3  = h2r[mt][3] + eluf(T2[mt][3] + vb2v);
            int col = mt * 32 + wv * 16 + n16;        // v*32 + c concat layout
            int r0  = (quad * 4) * 104 + col;
            uint u01 = pack2(x0, x1), u23 = pack2(x2v, x3);
            shB[r0]       = (ushort)u01;
            shB[r0 + 104] = (ushort)(u01 >> 16);
            shB[r0 + 208] = (ushort)u23;
            shB[r0 + 312] = (ushort)(u23 >> 16);
        }
        __syncthreads();                              // BAR5: x2 ready

        // ---- r1 = elu(x2 @ R1^T + rb1) ----
        f32x4 CR = Z;
#pragma unroll
        for (int ks = 0; ks < 3; ++ks) {              // K=96
            bf16x8 a = *(const bf16x8*)(shB + n16 * 104 + ks * 32 + quad * 8);
            bf16x8 b = *(const bf16x8*)(R1p + ks * 32);
            CR = __builtin_amdgcn_mfma_f32_16x16x32_bf16(a, b, CR, 0, 0, 0);
        }
        // r1 -> shC [16][40] (h2 readers drained at BAR4; clobbered pads stay finite)
        {
            float e0 = eluf(CR[0] + rb1v);
            float e1 = eluf(CR[1] + rb1v);
            float e2 = eluf(CR[2] + rb1v);
            float e3 = eluf(CR[3] + rb1v);
            int r0 = (quad * 4) * 40 + wv * 16 + n16;
            uint u01 = pack2(e0, e1), u23 = pack2(e2, e3);
            shC[r0]       = (ushort)u01;
            shC[r0 + 40]  = (ushort)(u01 >> 16);
            shC[r0 + 80]  = (ushort)u23;
            shC[r0 + 120] = (ushort)(u23 >> 16);
        }
        __syncthreads();                              // BAR6: r1 ready

        // ---- r2 = elu(r1 @ R2^T + rb2) -> fp32 shA [16][20] ----
        f32x4 C3 = Z;
        {
            bf16x8 a = *(const bf16x8*)(shC + n16 * 40 + quad * 8);
            C3 = __builtin_amdgcn_mfma_f32_16x16x32_bf16(a, R2f, C3, 0, 0, 0);
        }
        // r2 -> shA fp32 (t1 readers drained at BAR5)
        {
            float* r2b = (float*)shA;
#pragma unroll
            for (int rr = 0; rr < 2; ++rr) {          // wave wv writes r = 2wv+rr
                int r = 2 * wv + rr;
                r2b[(quad * 4 + r) * 20 + n16] = eluf(C3[r] + rb2v);
            }
        }
        __syncthreads();                              // BAR7: r2 ready

        // ---- final 16 -> 3 + sigmoid, coalesced store ----
        // (reads shA only; next iteration's shA writes are behind BAR1+BAR2)
        if (fthr) {
            const float4* rr = (const float4*)r2row;
            float4 a0 = rr[0], a1 = rr[1], a2 = rr[2], a3 = rr[3];
            float s = rb3c;
            s += a0.x * q0.x + a0.y * q0.y + a0.z * q0.z + a0.w * q0.w;
            s += a1.x * q1.x + a1.y * q1.y + a1.z * q1.z + a1.w * q1.w;
            s += a2.x * q2.x + a2.y * q2.y + a2.z * q2.z + a2.w * q2.w;
            s += a3.x * q3.x + a3.y * q3.y + a3.z * q3.z + a3.w * q3.w;
            o2[tid] = sigm(s);
        }

        // advance per-tile pointers by one grid-stride step (NBLK tiles)
        fin  += STRIDE * 105;
        brow += STRIDE * 105;
        orgb += STRIDE * 9;
        o2   += STRIDE * 3;
    }
}

extern "C" void kernel_launch(void* const* d_in, const int* in_sizes, int n_in,
                              void* d_out, int out_size, void* d_ws, size_t ws_size,
                              hipStream_t stream) {
    const float* feat = (const float*)d_in[0];
    const float* bw1  = (const float*)d_in[1];
    const float* bb1  = (const float*)d_in[2];
    const float* bw2  = (const float*)d_in[3];
    const float* bb2  = (const float*)d_in[4];
    const float* vw1  = (const float*)d_in[5];
    const float* vb1  = (const float*)d_in[6];
    const float* vw2  = (const float*)d_in[7];
    const float* vb2  = (const float*)d_in[8];
    const float* rw1  = (const float*)d_in[9];
    const float* rb1  = (const float*)d_in[10];
    const float* rw2  = (const float*)d_in[11];
    const float* rb2  = (const float*)d_in[12];
    const float* rw3  = (const float*)d_in[13];
    const float* rb3  = (const float*)d_in[14];
    ushort* w  = (ushort*)d_ws;
    float* out = (float*)d_out;

    hipLaunchKernelGGL(prep_k, dim3(77), dim3(256), 0, stream,
                       bw1, bw2, vw1, vw2, rw1, rw2, w);
    hipLaunchKernelGGL(mlp_k, dim3(NBLK), dim3(128), 0, stream,
                       feat, w, bb1, bb2, vb1, vb2, rb1, rb2, rw3, rb3, out);
}

// Round 4
// 431.980 us; speedup vs baseline: 1.1204x; 1.1011x over previous
//
#include <hip/hip_runtime.h>
#include <hip/hip_bf16.h>

// Problem constants (R=4096, S=128, V=3, F=35)
#define NPTS      524288            // R*S
#define OUT2_BASE 4718592           // NPTS*9  (rgb_in elements)
#define NTILES    32768             // NPTS/16

using bf16x8 = __attribute__((ext_vector_type(8))) short;   // MFMA A/B frag
using f32x4  = __attribute__((ext_vector_type(4))) float;   // MFMA C/D frag

// Weight workspace (ushort/bf16 in d_ws), [N][K] row-major, K padded, pads ZEROED:
//   WG [64][96]  @ 0      = bw1 mean part at cols 0..34, VAR part at cols 40..74
//                           (cols 35..39, 75..95 = 0) -- matches Xg LDS layout below
//   WF [64][72]  @ 6144   = bw1[:, 70:105](view part),  cols 35..71 = 0
//   W2 [32][72]  @ 10752  = bw2,  cols 64..71 = 0
//   V1 [32][40]  @ 13056  = vw1/3 (x/num_views folded), cols 32..39 = 0
//   V2 [32][40]  @ 14336  = vw2,  cols 32..39 = 0
//   R1 [32][104] @ 15616  = rw1,  cols 96..103 = 0
//   R2 [16][40]  @ 18944  = rw2,  cols 32..39 = 0

__device__ __forceinline__ ushort f2bf(float f) {
    union { float f; unsigned u; } v; v.f = f;
    unsigned u = v.u;
    unsigned r = u + 0x7fffu + ((u >> 16) & 1u);   // RTNE
    return (ushort)(r >> 16);
}
__device__ __forceinline__ uint pack2(float a, float b) {   // lo=bf16(a), hi=bf16(b)
    union { __hip_bfloat162 h; uint u; } cv;
    cv.h = __float22bfloat162_rn(make_float2(a, b));
    return cv.u;
}
__device__ __forceinline__ float eluf(float x) {
    return fmaxf(x, 0.f) + __expf(fminf(x, 0.f)) - 1.f;
}
__device__ __forceinline__ float sigm(float x) { return 1.f / (1.f + __expf(-x)); }

// unaligned-safe 8-float load (feat rows are 105 floats -> only 4B-aligned)
__device__ __forceinline__ void load8(const float* __restrict__ p, float* d) {
    __builtin_memcpy(d, p, 16);
    __builtin_memcpy(d + 4, p + 4, 16);
}

__global__ void prep_k(const float* __restrict__ bw1, const float* __restrict__ bw2,
                       const float* __restrict__ vw1, const float* __restrict__ vw2,
                       const float* __restrict__ rw1, const float* __restrict__ rw2,
                       ushort* __restrict__ w)
{
    int i = blockIdx.x * 256 + threadIdx.x;
    if (i < 6144) {                                   // WG [64][96] mean@0..34, var@40..74
        int n = i / 96, k = i % 96;
        float val = 0.f;
        if (k < 35)                 val = bw1[n * 105 + k];             // mean weights
        else if (k >= 40 && k < 75) val = bw1[n * 105 + 35 + (k - 40)]; // var weights
        w[i] = f2bf(val);
    } else if (i < 10752) {                           // WF [64][72]
        int t = i - 6144, n = t / 72, k = t % 72;
        w[i] = f2bf(k < 35 ? bw1[n * 105 + 70 + k] : 0.f);
    } else if (i < 13056) {                           // W2 [32][72]
        int t = i - 10752, n = t / 72, k = t % 72;
        w[i] = f2bf(k < 64 ? bw2[n * 64 + k] : 0.f);
    } else if (i < 14336) {                           // V1 [32][40] (/3 folded)
        int t = i - 13056, n = t / 40, k = t % 40;
        w[i] = f2bf(k < 32 ? vw1[n * 32 + k] * (1.f / 3.f) : 0.f);
    } else if (i < 15616) {                           // V2 [32][40]
        int t = i - 14336, n = t / 40, k = t % 40;
        w[i] = f2bf(k < 32 ? vw2[n * 32 + k] : 0.f);
    } else if (i < 18944) {                           // R1 [32][104]
        int t = i - 15616, n = t / 104, k = t % 104;
        w[i] = f2bf(k < 96 ? rw1[n * 96 + k] : 0.f);
    } else if (i < 19584) {                           // R2 [16][40]
        int t = i - 18944, n = t / 40, k = t % 40;
        w[i] = f2bf(k < 32 ? rw2[n * 32 + k] : 0.f);
    }
}

// 2 waves/block, 16 points/block, 32768 blocks (non-persistent: persistence
// quadrupled FETCH_SIZE order-independently, R2/R3 post-mortems).
// TRANSPOSED-C scheme: every MFMA is called as mfma(W_frag, X_frag, C) so
// D[row=feature=quad*4+reg][col=point=n16]. Each lane's 4 accumulator values are
// 4 consecutive features of one point -> epilogue stores are ONE ds_write_b64
// into the row-major [point][feature] LDS tiles (was 4 scattered ds_write_b16).
// X-side and W-side fragment loads are identical to the non-swapped form.
// LDS timeline-aliased (17.2 KB):
//   shA 6912 B: h1[48][72] -> t1[48][72] -> r2b fp32[16][20]
//   shB 3328 B: Xg[16][96] -> x2[16][104]
//   shC 6912 B: Xf[48][72] -> h2[48][72] -> r1[16][40]
// 7 barriers (minimal chain; R0/R1 lifetime analysis).
__global__ __launch_bounds__(128, 4) void mlp_k(
    const float* __restrict__ feat, const ushort* __restrict__ w,
    const float* __restrict__ bb1, const float* __restrict__ bb2,
    const float* __restrict__ vb1, const float* __restrict__ vb2,
    const float* __restrict__ rb1, const float* __restrict__ rb2,
    const float* __restrict__ rw3, const float* __restrict__ rb3,
    float* __restrict__ out)
{
    __shared__ __align__(16) ushort shA[3456];
    __shared__ __align__(16) ushort shB[1664];
    __shared__ __align__(16) ushort shC[3456];

    const int tid  = threadIdx.x;
    const int wv   = tid >> 6;          // wave id 0/1
    const int lane = tid & 63;
    const int n16  = lane & 15;
    const int quad = lane >> 4;
    const long long pbase = (long long)blockIdx.x * 16;

    const ushort* WG = w;
    const ushort* WF = w + 6144;
    const ushort* W2 = w + 10752;
    const ushort* V1 = w + 13056;
    const ushort* V2 = w + 14336;
    const ushort* R1 = w + 15616;
    const ushort* R2 = w + 18944;

    // per-reg biases: feature index = (block)*16 + quad*4 + reg  -> float4 loads
    const float4 bb1q0 = *(const float4*)(bb1 + (wv * 2 + 0) * 16 + quad * 4);
    const float4 bb1q1 = *(const float4*)(bb1 + (wv * 2 + 1) * 16 + quad * 4);
    const float4 bb2q  = *(const float4*)(bb2 + wv * 16 + quad * 4);
    const float4 vb1q  = *(const float4*)(vb1 + wv * 16 + quad * 4);
    const float4 vb2q  = *(const float4*)(vb2 + wv * 16 + quad * 4);
    const float4 rb1q  = *(const float4*)(rb1 + wv * 16 + quad * 4);
    const float4 rb2q  = *(const float4*)(rb2 + quad * 4);

    // ---- phase A: targeted pad zero-fill + build Xg/Xf from GLOBAL + rgb_in ----
    {
        const uint4 z = make_uint4(0u, 0u, 0u, 0u);
        uint4* zc = (uint4*)shC;                      // Xf pad cols 40..63, rows 0..47
        for (int i = tid; i < 144; i += 128) {
            int r = i / 3, c = i - r * 3;
            zc[r * 9 + 5 + c] = z;
        }
        if (tid < 32) {                               // Xg pad cols 80..95, rows 0..15
            uint4* zb = (uint4*)shB;
            int r = tid >> 1, c = tid & 1;
            zb[r * 12 + 10 + c] = z;
        }
        // rgb_in passthrough (fp32 exact)
        float* o1 = out + pbase * 9;
        for (int i = tid; i < 144; i += 128) {
            int p = i / 9, r = i - p * 9, v = r / 3, c = r - v * 3;
            o1[i] = feat[(pbase + p) * 105 + v * 35 + c];
        }
        // main build: 80 threads, one (point, 8-feature group) each
        if (tid < 80) {
            int p  = tid / 5;           // 0..15
            int g  = tid - p * 5;       // 0..4
            int k8 = g * 8;             // 0,8,16,24,32 (tail group has 3 valid feats)
            const float* row = feat + (pbase + p) * 105;
            float X0[8], X1[8], X2[8];
            load8(row + k8,      X0);   // view 0 (tail overread: finite, zero-weight)
            load8(row + 35 + k8, X1);   // view 1
            if (k8 == 32 && (pbase + p) == (long long)NPTS - 1) {
                X2[0] = row[102]; X2[1] = row[103]; X2[2] = row[104];
                X2[3] = 0.f; X2[4] = 0.f; X2[5] = 0.f; X2[6] = 0.f; X2[7] = 0.f;
            } else {
                load8(row + 70 + k8, X2);   // view 2
            }
            float M[8], VV[8];
#pragma unroll
            for (int j = 0; j < 8; ++j) {
                float a = X0[j], b = X1[j], c = X2[j];
                float m  = (a + b + c) * (1.f / 3.f);
                float da = a - m, db = b - m, dc = c - m;
                M[j]  = m;
                VV[j] = (da * da + db * db + dc * dc) * (1.f / 3.f);
            }
            *(uint4*)(shC + p * 72 + k8) =
                make_uint4(pack2(X0[0], X0[1]), pack2(X0[2], X0[3]),
                           pack2(X0[4], X0[5]), pack2(X0[6], X0[7]));
            *(uint4*)(shC + (16 + p) * 72 + k8) =
                make_uint4(pack2(X1[0], X1[1]), pack2(X1[2], X1[3]),
                           pack2(X1[4], X1[5]), pack2(X1[6], X1[7]));
            *(uint4*)(shC + (32 + p) * 72 + k8) =
                make_uint4(pack2(X2[0], X2[1]), pack2(X2[2], X2[3]),
                           pack2(X2[4], X2[5]), pack2(X2[6], X2[7]));
            *(uint4*)(shB + p * 96 + k8) =
                make_uint4(pack2(M[0], M[1]), pack2(M[2], M[3]),
                           pack2(M[4], M[5]), pack2(M[6], M[7]));
            *(uint4*)(shB + p * 96 + 40 + k8) =
                make_uint4(pack2(VV[0], VV[1]), pack2(VV[2], VV[3]),
                           pack2(VV[4], VV[5]), pack2(VV[6], VV[7]));
        }
    }
    __syncthreads();                                  // BAR1: Xg/Xf ready

    const f32x4 Z = {0.f, 0.f, 0.f, 0.f};

    // ---- layer 1: D[feat][point] = mfma(W, X) ----
    f32x4 Cg[2]    = {Z, Z};
    f32x4 Cf[3][2] = {{Z, Z}, {Z, Z}, {Z, Z}};
#pragma unroll
    for (int ks = 0; ks < 3; ++ks) {                  // K=96 : [mean|var]
        bf16x8 xg = *(const bf16x8*)(shB + n16 * 96 + ks * 32 + quad * 8);
#pragma unroll
        for (int ntl = 0; ntl < 2; ++ntl) {
            bf16x8 wg = *(const bf16x8*)(WG + ((wv * 2 + ntl) * 16 + n16) * 96 + ks * 32 + quad * 8);
            Cg[ntl] = __builtin_amdgcn_mfma_f32_16x16x32_bf16(wg, xg, Cg[ntl], 0, 0, 0);
        }
    }
#pragma unroll
    for (int ks = 0; ks < 2; ++ks) {                  // K=64 : view feat
        bf16x8 x0 = *(const bf16x8*)(shC + (0 * 16 + n16) * 72 + ks * 32 + quad * 8);
        bf16x8 x1 = *(const bf16x8*)(shC + (1 * 16 + n16) * 72 + ks * 32 + quad * 8);
        bf16x8 x2 = *(const bf16x8*)(shC + (2 * 16 + n16) * 72 + ks * 32 + quad * 8);
#pragma unroll
        for (int ntl = 0; ntl < 2; ++ntl) {
            bf16x8 wf = *(const bf16x8*)(WF + ((wv * 2 + ntl) * 16 + n16) * 72 + ks * 32 + quad * 8);
            Cf[0][ntl] = __builtin_amdgcn_mfma_f32_16x16x32_bf16(wf, x0, Cf[0][ntl], 0, 0, 0);
            Cf[1][ntl] = __builtin_amdgcn_mfma_f32_16x16x32_bf16(wf, x1, Cf[1][ntl], 0, 0, 0);
            Cf[2][ntl] = __builtin_amdgcn_mfma_f32_16x16x32_bf16(wf, x2, Cf[2][ntl], 0, 0, 0);
        }
    }
    // h1 = elu(Cf + Cg + bb1) -> shA [48 = view*16+point][72]
    // lane owns point n16 (of view mt), features (wv*2+ntl)*16 + quad*4 + 0..3
#pragma unroll
    for (int mt = 0; mt < 3; ++mt)
#pragma unroll
        for (int ntl = 0; ntl < 2; ++ntl) {
            const float4 bq = ntl ? bb1q1 : bb1q0;
            float e0 = eluf(Cf[mt][ntl][0] + Cg[ntl][0] + bq.x);
            float e1 = eluf(Cf[mt][ntl][1] + Cg[ntl][1] + bq.y);
            float e2 = eluf(Cf[mt][ntl][2] + Cg[ntl][2] + bq.z);
            float e3 = eluf(Cf[mt][ntl][3] + Cg[ntl][3] + bq.w);
            uint2 u; u.x = pack2(e0, e1); u.y = pack2(e2, e3);
            *(uint2*)(shA + (mt * 16 + n16) * 72 + (wv * 2 + ntl) * 16 + quad * 4) = u;
        }
    __syncthreads();                                  // BAR2: h1 ready (Xf readers drained)

    // ---- layer 2 ----
    f32x4 C2[3] = {Z, Z, Z};
#pragma unroll
    for (int ks = 0; ks < 2; ++ks) {
        bf16x8 x0 = *(const bf16x8*)(shA + (0 * 16 + n16) * 72 + ks * 32 + quad * 8);
        bf16x8 x1 = *(const bf16x8*)(shA + (1 * 16 + n16) * 72 + ks * 32 + quad * 8);
        bf16x8 x2 = *(const bf16x8*)(shA + (2 * 16 + n16) * 72 + ks * 32 + quad * 8);
        bf16x8 w2 = *(const bf16x8*)(W2 + (wv * 16 + n16) * 72 + ks * 32 + quad * 8);
        C2[0] = __builtin_amdgcn_mfma_f32_16x16x32_bf16(w2, x0, C2[0], 0, 0, 0);
        C2[1] = __builtin_amdgcn_mfma_f32_16x16x32_bf16(w2, x1, C2[1], 0, 0, 0);
        C2[2] = __builtin_amdgcn_mfma_f32_16x16x32_bf16(w2, x2, C2[2], 0, 0, 0);
    }
    // h2 -> shC (Xf readers drained at BAR2); keep elu'd values for residual
    float h2r[3][4];
#pragma unroll
    for (int mt = 0; mt < 3; ++mt) {
        float e0 = eluf(C2[mt][0] + bb2q.x);
        float e1 = eluf(C2[mt][1] + bb2q.y);
        float e2 = eluf(C2[mt][2] + bb2q.z);
        float e3 = eluf(C2[mt][3] + bb2q.w);
        h2r[mt][0] = e0; h2r[mt][1] = e1; h2r[mt][2] = e2; h2r[mt][3] = e3;
        uint2 u; u.x = pack2(e0, e1); u.y = pack2(e2, e3);
        *(uint2*)(shC + (mt * 16 + n16) * 72 + wv * 16 + quad * 4) = u;
    }
    __syncthreads();                                  // BAR3: h2 ready

    // ---- vis layer 1 (K=32, cols 0..31 of shC) ----
    f32x4 T1[3] = {Z, Z, Z};
    {
        bf16x8 x0 = *(const bf16x8*)(shC + (0 * 16 + n16) * 72 + quad * 8);
        bf16x8 x1 = *(const bf16x8*)(shC + (1 * 16 + n16) * 72 + quad * 8);
        bf16x8 x2 = *(const bf16x8*)(shC + (2 * 16 + n16) * 72 + quad * 8);
        bf16x8 v1 = *(const bf16x8*)(V1 + (wv * 16 + n16) * 40 + quad * 8);
        T1[0] = __builtin_amdgcn_mfma_f32_16x16x32_bf16(v1, x0, T1[0], 0, 0, 0);
        T1[1] = __builtin_amdgcn_mfma_f32_16x16x32_bf16(v1, x1, T1[1], 0, 0, 0);
        T1[2] = __builtin_amdgcn_mfma_f32_16x16x32_bf16(v1, x2, T1[2], 0, 0, 0);
    }
    // t1 -> shA (h1 readers drained at BAR3)
#pragma unroll
    for (int mt = 0; mt < 3; ++mt) {
        float e0 = eluf(T1[mt][0] + vb1q.x);
        float e1 = eluf(T1[mt][1] + vb1q.y);
        float e2 = eluf(T1[mt][2] + vb1q.z);
        float e3 = eluf(T1[mt][3] + vb1q.w);
        uint2 u; u.x = pack2(e0, e1); u.y = pack2(e2, e3);
        *(uint2*)(shA + (mt * 16 + n16) * 72 + wv * 16 + quad * 4) = u;
    }
    __syncthreads();                                  // BAR4: t1 ready

    // ---- vis layer 2 + residual -> x2 (shB [16][104]) ----
    f32x4 T2[3] = {Z, Z, Z};
    {
        bf16x8 x0 = *(const bf16x8*)(shA + (0 * 16 + n16) * 72 + quad * 8);
        bf16x8 x1 = *(const bf16x8*)(shA + (1 * 16 + n16) * 72 + quad * 8);
        bf16x8 x2 = *(const bf16x8*)(shA + (2 * 16 + n16) * 72 + quad * 8);
        bf16x8 v2 = *(const bf16x8*)(V2 + (wv * 16 + n16) * 40 + quad * 8);
        T2[0] = __builtin_amdgcn_mfma_f32_16x16x32_bf16(v2, x0, T2[0], 0, 0, 0);
        T2[1] = __builtin_amdgcn_mfma_f32_16x16x32_bf16(v2, x1, T2[1], 0, 0, 0);
        T2[2] = __builtin_amdgcn_mfma_f32_16x16x32_bf16(v2, x2, T2[2], 0, 0, 0);
    }
    // x2 -> shB (Xg readers drained at BAR2); col = view*32 + feature
#pragma unroll
    for (int mt = 0; mt < 3; ++mt) {
        float x0 = h2r[mt][0] + eluf(T2[mt][0] + vb2q.x);
        float x1 = h2r[mt][1] + eluf(T2[mt][1] + vb2q.y);
        float x2v = h2r[mt][2] + eluf(T2[mt][2] + vb2q.z);
        float x3 = h2r[mt][3] + eluf(T2[mt][3] + vb2q.w);
        uint2 u; u.x = pack2(x0, x1); u.y = pack2(x2v, x3);
        *(uint2*)(shB + n16 * 104 + mt * 32 + wv * 16 + quad * 4) = u;
    }
    __syncthreads();                                  // BAR5: x2 ready

    // ---- r1 = elu(x2 @ R1^T + rb1) ----
    f32x4 CR = Z;
#pragma unroll
    for (int ks = 0; ks < 3; ++ks) {                  // K=96
        bf16x8 xb = *(const bf16x8*)(shB + n16 * 104 + ks * 32 + quad * 8);
        bf16x8 r1w = *(const bf16x8*)(R1 + (wv * 16 + n16) * 104 + ks * 32 + quad * 8);
        CR = __builtin_amdgcn_mfma_f32_16x16x32_bf16(r1w, xb, CR, 0, 0, 0);
    }
    // r1 -> shC [16][40] (h2 readers drained at BAR4)
    {
        float e0 = eluf(CR[0] + rb1q.x);
        float e1 = eluf(CR[1] + rb1q.y);
        float e2 = eluf(CR[2] + rb1q.z);
        float e3 = eluf(CR[3] + rb1q.w);
        uint2 u; u.x = pack2(e0, e1); u.y = pack2(e2, e3);
        *(uint2*)(shC + n16 * 40 + wv * 16 + quad * 4) = u;
    }
    __syncthreads();                                  // BAR6: r1 ready

    // ---- r2 = elu(r1 @ R2^T + rb2) -> fp32 shA [16][20] ----
    f32x4 C3 = Z;
    {
        bf16x8 xb = *(const bf16x8*)(shC + n16 * 40 + quad * 8);
        bf16x8 r2w = *(const bf16x8*)(R2 + n16 * 40 + quad * 8);
        C3 = __builtin_amdgcn_mfma_f32_16x16x32_bf16(r2w, xb, C3, 0, 0, 0);
    }
    // r2 -> shA fp32 (t1 readers drained at BAR5). Both waves compute identical
    // C3; wave 0 stores one float4 per lane (point n16, feats quad*4..+3).
    if (wv == 0) {
        float4 rv;
        rv.x = eluf(C3[0] + rb2q.x);
        rv.y = eluf(C3[1] + rb2q.y);
        rv.z = eluf(C3[2] + rb2q.z);
        rv.w = eluf(C3[3] + rb2q.w);
        *(float4*)((float*)shA + n16 * 20 + quad * 4) = rv;
    }
    __syncthreads();                                  // BAR7: r2 ready

    // ---- final 16 -> 3 + sigmoid (fp32), coalesced store ----
    if (tid < 48) {
        const float* r2b = (const float*)shA;
        int p = tid / 3, c = tid - p * 3;
        const float4* rr = (const float4*)(r2b + p * 20);
        const float4* w3 = (const float4*)(rw3 + c * 16);
        float4 a0 = rr[0], a1 = rr[1], a2 = rr[2], a3 = rr[3];
        float4 q0 = w3[0], q1 = w3[1], q2 = w3[2], q3 = w3[3];
        float s = rb3[c];
        s += a0.x * q0.x + a0.y * q0.y + a0.z * q0.z + a0.w * q0.w;
        s += a1.x * q1.x + a1.y * q1.y + a1.z * q1.z + a1.w * q1.w;
        s += a2.x * q2.x + a2.y * q2.y + a2.z * q2.z + a2.w * q2.w;
        s += a3.x * q3.x + a3.y * q3.y + a3.z * q3.z + a3.w * q3.w;
        out[OUT2_BASE + pbase * 3 + tid] = sigm(s);
    }
}

extern "C" void kernel_launch(void* const* d_in, const int* in_sizes, int n_in,
                              void* d_out, int out_size, void* d_ws, size_t ws_size,
                              hipStream_t stream) {
    const float* feat = (const float*)d_in[0];
    const float* bw1  = (const float*)d_in[1];
    const float* bb1  = (const float*)d_in[2];
    const float* bw2  = (const float*)d_in[3];
    const float* bb2  = (const float*)d_in[4];
    const float* vw1  = (const float*)d_in[5];
    const float* vb1  = (const float*)d_in[6];
    const float* vw2  = (const float*)d_in[7];
    const float* vb2  = (const float*)d_in[8];
    const float* rw1  = (const float*)d_in[9];
    const float* rb1  = (const float*)d_in[10];
    const float* rw2  = (const float*)d_in[11];
    const float* rb2  = (const float*)d_in[12];
    const float* rw3  = (const float*)d_in[13];
    const float* rb3  = (const float*)d_in[14];
    ushort* w  = (ushort*)d_ws;
    float* out = (float*)d_out;

    hipLaunchKernelGGL(prep_k, dim3(77), dim3(256), 0, stream,
                       bw1, bw2, vw1, vw2, rw1, rw2, w);
    hipLaunchKernelGGL(mlp_k, dim3(NTILES), dim3(128), 0, stream,
                       feat, w, bb1, bb2, vb1, vb2, rb1, rb2, rw3, rb3, out);
}

// Round 5
// 421.966 us; speedup vs baseline: 1.1469x; 1.0237x over previous
//
#include <hip/hip_runtime.h>
#include <hip/hip_bf16.h>

// Problem constants (R=4096, S=128, V=3, F=35)
#define NPTS      524288            // R*S
#define OUT2_BASE 4718592           // NPTS*9  (rgb_in elements)
#define NBLK32    16384             // NPTS/32

using bf16x8 = __attribute__((ext_vector_type(8))) short;   // MFMA A/B frag
using f32x4  = __attribute__((ext_vector_type(4))) float;   // MFMA C/D frag

// Weight workspace (ushort/bf16 in d_ws), [N][K] row-major, K padded, pads ZEROED:
//   WG [64][96]  @ 0      = bw1 mean part at cols 0..34, VAR part at cols 40..74
//                           (cols 35..39, 75..95 = 0) -- matches Xg LDS layout below
//   WF [64][72]  @ 6144   = bw1[:, 70:105](view part),  cols 35..71 = 0
//   W2 [32][72]  @ 10752  = bw2,  cols 64..71 = 0
//   V1 [32][40]  @ 13056  = vw1/3 (x/num_views folded), cols 32..39 = 0
//   V2 [32][40]  @ 14336  = vw2,  cols 32..39 = 0
//   R1 [32][104] @ 15616  = rw1,  cols 96..103 = 0
//   R2 [16][40]  @ 18944  = rw2,  cols 32..39 = 0

__device__ __forceinline__ ushort f2bf(float f) {
    union { float f; unsigned u; } v; v.f = f;
    unsigned u = v.u;
    unsigned r = u + 0x7fffu + ((u >> 16) & 1u);   // RTNE
    return (ushort)(r >> 16);
}
__device__ __forceinline__ uint pack2(float a, float b) {   // lo=bf16(a), hi=bf16(b)
    union { __hip_bfloat162 h; uint u; } cv;
    cv.h = __float22bfloat162_rn(make_float2(a, b));
    return cv.u;
}
__device__ __forceinline__ float eluf(float x) {
    return fmaxf(x, 0.f) + __expf(fminf(x, 0.f)) - 1.f;
}
__device__ __forceinline__ float sigm(float x) { return 1.f / (1.f + __expf(-x)); }

// unaligned-safe 8-float load (feat rows are 105 floats -> only 4B-aligned)
__device__ __forceinline__ void load8(const float* __restrict__ p, float* d) {
    __builtin_memcpy(d, p, 16);
    __builtin_memcpy(d + 4, p + 4, 16);
}

__global__ void prep_k(const float* __restrict__ bw1, const float* __restrict__ bw2,
                       const float* __restrict__ vw1, const float* __restrict__ vw2,
                       const float* __restrict__ rw1, const float* __restrict__ rw2,
                       ushort* __restrict__ w)
{
    int i = blockIdx.x * 256 + threadIdx.x;
    if (i < 6144) {                                   // WG [64][96] mean@0..34, var@40..74
        int n = i / 96, k = i % 96;
        float val = 0.f;
        if (k < 35)                 val = bw1[n * 105 + k];             // mean weights
        else if (k >= 40 && k < 75) val = bw1[n * 105 + 35 + (k - 40)]; // var weights
        w[i] = f2bf(val);
    } else if (i < 10752) {                           // WF [64][72]
        int t = i - 6144, n = t / 72, k = t % 72;
        w[i] = f2bf(k < 35 ? bw1[n * 105 + 70 + k] : 0.f);
    } else if (i < 13056) {                           // W2 [32][72]
        int t = i - 10752, n = t / 72, k = t % 72;
        w[i] = f2bf(k < 64 ? bw2[n * 64 + k] : 0.f);
    } else if (i < 14336) {                           // V1 [32][40] (/3 folded)
        int t = i - 13056, n = t / 40, k = t % 40;
        w[i] = f2bf(k < 32 ? vw1[n * 32 + k] * (1.f / 3.f) : 0.f);
    } else if (i < 15616) {                           // V2 [32][40]
        int t = i - 14336, n = t / 40, k = t % 40;
        w[i] = f2bf(k < 32 ? vw2[n * 32 + k] : 0.f);
    } else if (i < 18944) {                           // R1 [32][104]
        int t = i - 15616, n = t / 104, k = t % 104;
        w[i] = f2bf(k < 96 ? rw1[n * 96 + k] : 0.f);
    } else if (i < 19584) {                           // R2 [16][40]
        int t = i - 18944, n = t / 40, k = t % 40;
        w[i] = f2bf(k < 32 ? rw2[n * 32 + k] : 0.f);
    }
}

// 4 waves/block (256 thr), 32 points/block, 16384 blocks. Wave (wv2,wvn):
// wv2 = M-half (points wv2*16+n16), wvn = N-half (feature cols wvn*16.. of each layer;
// layer1 N=64 -> wvn covers 2 sub-tiles). Per-wave instruction stream identical to the
// 2-wave/16-pt version; barriers amortized over 2x points, occupancy 42%->~50%
// (4 blocks/CU x 33.8 KB LDS, 16 waves/CU). Non-persistent (R2/R3: persistence
// quadruples FETCH order-independently). TRANSPOSED-C: mfma(W,X) -> lane holds
// 4 consecutive features of one point -> single uint2/float4 epilogue stores.
// LDS timeline-aliased (33.8 KB):
//   shA 13824 B: h1[96][72] -> t1[96][72] -> r2b fp32[32][20]
//   shB  6656 B: Xg[32][96] -> x2[32][104]
//   shC 13824 B: Xf[96][72] -> h2[96][72] -> r1[32][40]
// 7 barriers (minimal chain; R0/R1 lifetime analysis, re-verified for 32-pt tiles).
__global__ __launch_bounds__(256, 4) void mlp_k(
    const float* __restrict__ feat, const ushort* __restrict__ w,
    const float* __restrict__ bb1, const float* __restrict__ bb2,
    const float* __restrict__ vb1, const float* __restrict__ vb2,
    const float* __restrict__ rb1, const float* __restrict__ rb2,
    const float* __restrict__ rw3, const float* __restrict__ rb3,
    float* __restrict__ out)
{
    __shared__ __align__(16) ushort shA[6912];   // 96*72
    __shared__ __align__(16) ushort shB[3328];   // 32*104
    __shared__ __align__(16) ushort shC[6912];   // 96*72

    const int tid  = threadIdx.x;
    const int wave = tid >> 6;          // 0..3
    const int wv2  = wave >> 1;         // M half
    const int wvn  = wave & 1;          // N half
    const int lane = tid & 63;
    const int n16  = lane & 15;
    const int quad = lane >> 4;
    const int prow = wv2 * 16 + n16;    // this lane's point row (0..31)
    const long long pbase = (long long)blockIdx.x * 32;

    const ushort* WG = w;
    const ushort* WF = w + 6144;
    const ushort* W2 = w + 10752;
    const ushort* V1 = w + 13056;
    const ushort* V2 = w + 14336;
    const ushort* R1 = w + 15616;
    const ushort* R2 = w + 18944;

    // per-reg biases: feature index = tileBase + quad*4 + reg -> float4 loads
    const float4 bb1q0 = *(const float4*)(bb1 + (wvn * 2 + 0) * 16 + quad * 4);
    const float4 bb1q1 = *(const float4*)(bb1 + (wvn * 2 + 1) * 16 + quad * 4);
    const float4 bb2q  = *(const float4*)(bb2 + wvn * 16 + quad * 4);
    const float4 vb1q  = *(const float4*)(vb1 + wvn * 16 + quad * 4);
    const float4 vb2q  = *(const float4*)(vb2 + wvn * 16 + quad * 4);
    const float4 rb1q  = *(const float4*)(rb1 + wvn * 16 + quad * 4);
    const float4 rb2q  = *(const float4*)(rb2 + quad * 4);

    // ---- phase A: targeted pad zero-fill + build Xg/Xf from GLOBAL + rgb_in ----
    {
        const uint4 z = make_uint4(0u, 0u, 0u, 0u);
        uint4* zc = (uint4*)shC;                      // Xf pad cols 40..63, rows 0..95
        for (int i = tid; i < 288; i += 256) {        // 96 rows x 3 uint4 (row = 9 uint4)
            int r = i / 3, c = i - r * 3;
            zc[r * 9 + 5 + c] = z;
        }
        if (tid < 64) {                               // Xg pad cols 80..95, rows 0..31
            uint4* zb = (uint4*)shB;                  // row = 12 uint4 (192 B)
            int r = tid >> 1, c = tid & 1;
            zb[r * 12 + 10 + c] = z;
        }
        // rgb_in passthrough (fp32 exact): 32 pts x 9
        float* o1 = out + pbase * 9;
        for (int i = tid; i < 288; i += 256) {
            int p = i / 9, r = i - p * 9, v = r / 3, c = r - v * 3;
            o1[i] = feat[(pbase + p) * 105 + v * 35 + c];
        }
        // main build: 160 threads, one (point, 8-feature group) each
        if (tid < 160) {
            int p  = tid / 5;           // 0..31
            int g  = tid - p * 5;       // 0..4
            int k8 = g * 8;             // 0,8,16,24,32 (tail group has 3 valid feats)
            const float* row = feat + (pbase + p) * 105;
            float X0[8], X1[8], X2[8];
            load8(row + k8,      X0);   // view 0 (tail overread: finite, zero-weight)
            load8(row + 35 + k8, X1);   // view 1
            if (k8 == 32 && (pbase + p) == (long long)NPTS - 1) {
                X2[0] = row[102]; X2[1] = row[103]; X2[2] = row[104];
                X2[3] = 0.f; X2[4] = 0.f; X2[5] = 0.f; X2[6] = 0.f; X2[7] = 0.f;
            } else {
                load8(row + 70 + k8, X2);   // view 2
            }
            float M[8], VV[8];
#pragma unroll
            for (int j = 0; j < 8; ++j) {
                float a = X0[j], b = X1[j], c = X2[j];
                float m  = (a + b + c) * (1.f / 3.f);
                float da = a - m, db = b - m, dc = c - m;
                M[j]  = m;
                VV[j] = (da * da + db * db + dc * dc) * (1.f / 3.f);
            }
            *(uint4*)(shC + p * 72 + k8) =
                make_uint4(pack2(X0[0], X0[1]), pack2(X0[2], X0[3]),
                           pack2(X0[4], X0[5]), pack2(X0[6], X0[7]));
            *(uint4*)(shC + (32 + p) * 72 + k8) =
                make_uint4(pack2(X1[0], X1[1]), pack2(X1[2], X1[3]),
                           pack2(X1[4], X1[5]), pack2(X1[6], X1[7]));
            *(uint4*)(shC + (64 + p) * 72 + k8) =
                make_uint4(pack2(X2[0], X2[1]), pack2(X2[2], X2[3]),
                           pack2(X2[4], X2[5]), pack2(X2[6], X2[7]));
            *(uint4*)(shB + p * 96 + k8) =
                make_uint4(pack2(M[0], M[1]), pack2(M[2], M[3]),
                           pack2(M[4], M[5]), pack2(M[6], M[7]));
            *(uint4*)(shB + p * 96 + 40 + k8) =
                make_uint4(pack2(VV[0], VV[1]), pack2(VV[2], VV[3]),
                           pack2(VV[4], VV[5]), pack2(VV[6], VV[7]));
        }
    }
    __syncthreads();                                  // BAR1: Xg/Xf ready

    const f32x4 Z = {0.f, 0.f, 0.f, 0.f};

    // ---- layer 1: D[feat][point] = mfma(W, X) ----
    f32x4 Cg[2]    = {Z, Z};
    f32x4 Cf[3][2] = {{Z, Z}, {Z, Z}, {Z, Z}};
#pragma unroll
    for (int ks = 0; ks < 3; ++ks) {                  // K=96 : [mean|var]
        bf16x8 xg = *(const bf16x8*)(shB + prow * 96 + ks * 32 + quad * 8);
#pragma unroll
        for (int ntl = 0; ntl < 2; ++ntl) {
            bf16x8 wg = *(const bf16x8*)(WG + ((wvn * 2 + ntl) * 16 + n16) * 96 + ks * 32 + quad * 8);
            Cg[ntl] = __builtin_amdgcn_mfma_f32_16x16x32_bf16(wg, xg, Cg[ntl], 0, 0, 0);
        }
    }
#pragma unroll
    for (int ks = 0; ks < 2; ++ks) {                  // K=64 : view feat
        bf16x8 x0 = *(const bf16x8*)(shC + (0 * 32 + prow) * 72 + ks * 32 + quad * 8);
        bf16x8 x1 = *(const bf16x8*)(shC + (1 * 32 + prow) * 72 + ks * 32 + quad * 8);
        bf16x8 x2 = *(const bf16x8*)(shC + (2 * 32 + prow) * 72 + ks * 32 + quad * 8);
#pragma unroll
        for (int ntl = 0; ntl < 2; ++ntl) {
            bf16x8 wf = *(const bf16x8*)(WF + ((wvn * 2 + ntl) * 16 + n16) * 72 + ks * 32 + quad * 8);
            Cf[0][ntl] = __builtin_amdgcn_mfma_f32_16x16x32_bf16(wf, x0, Cf[0][ntl], 0, 0, 0);
            Cf[1][ntl] = __builtin_amdgcn_mfma_f32_16x16x32_bf16(wf, x1, Cf[1][ntl], 0, 0, 0);
            Cf[2][ntl] = __builtin_amdgcn_mfma_f32_16x16x32_bf16(wf, x2, Cf[2][ntl], 0, 0, 0);
        }
    }
    // h1 = elu(Cf + Cg + bb1) -> shA [96 = view*32+point][72]
#pragma unroll
    for (int mt = 0; mt < 3; ++mt)
#pragma unroll
        for (int ntl = 0; ntl < 2; ++ntl) {
            const float4 bq = ntl ? bb1q1 : bb1q0;
            float e0 = eluf(Cf[mt][ntl][0] + Cg[ntl][0] + bq.x);
            float e1 = eluf(Cf[mt][ntl][1] + Cg[ntl][1] + bq.y);
            float e2 = eluf(Cf[mt][ntl][2] + Cg[ntl][2] + bq.z);
            float e3 = eluf(Cf[mt][ntl][3] + Cg[ntl][3] + bq.w);
            uint2 u; u.x = pack2(e0, e1); u.y = pack2(e2, e3);
            *(uint2*)(shA + (mt * 32 + prow) * 72 + (wvn * 2 + ntl) * 16 + quad * 4) = u;
        }
    __syncthreads();                                  // BAR2: h1 ready (Xf readers drained)

    // ---- layer 2 ----
    f32x4 C2[3] = {Z, Z, Z};
#pragma unroll
    for (int ks = 0; ks < 2; ++ks) {
        bf16x8 x0 = *(const bf16x8*)(shA + (0 * 32 + prow) * 72 + ks * 32 + quad * 8);
        bf16x8 x1 = *(const bf16x8*)(shA + (1 * 32 + prow) * 72 + ks * 32 + quad * 8);
        bf16x8 x2 = *(const bf16x8*)(shA + (2 * 32 + prow) * 72 + ks * 32 + quad * 8);
        bf16x8 w2 = *(const bf16x8*)(W2 + (wvn * 16 + n16) * 72 + ks * 32 + quad * 8);
        C2[0] = __builtin_amdgcn_mfma_f32_16x16x32_bf16(w2, x0, C2[0], 0, 0, 0);
        C2[1] = __builtin_amdgcn_mfma_f32_16x16x32_bf16(w2, x1, C2[1], 0, 0, 0);
        C2[2] = __builtin_amdgcn_mfma_f32_16x16x32_bf16(w2, x2, C2[2], 0, 0, 0);
    }
    // h2 -> shC (Xf readers drained at BAR2); keep elu'd values for residual
    float h2r[3][4];
#pragma unroll
    for (int mt = 0; mt < 3; ++mt) {
        float e0 = eluf(C2[mt][0] + bb2q.x);
        float e1 = eluf(C2[mt][1] + bb2q.y);
        float e2 = eluf(C2[mt][2] + bb2q.z);
        float e3 = eluf(C2[mt][3] + bb2q.w);
        h2r[mt][0] = e0; h2r[mt][1] = e1; h2r[mt][2] = e2; h2r[mt][3] = e3;
        uint2 u; u.x = pack2(e0, e1); u.y = pack2(e2, e3);
        *(uint2*)(shC + (mt * 32 + prow) * 72 + wvn * 16 + quad * 4) = u;
    }
    __syncthreads();                                  // BAR3: h2 ready

    // ---- vis layer 1 (K=32, cols 0..31 of shC) ----
    f32x4 T1[3] = {Z, Z, Z};
    {
        bf16x8 x0 = *(const bf16x8*)(shC + (0 * 32 + prow) * 72 + quad * 8);
        bf16x8 x1 = *(const bf16x8*)(shC + (1 * 32 + prow) * 72 + quad * 8);
        bf16x8 x2 = *(const bf16x8*)(shC + (2 * 32 + prow) * 72 + quad * 8);
        bf16x8 v1 = *(const bf16x8*)(V1 + (wvn * 16 + n16) * 40 + quad * 8);
        T1[0] = __builtin_amdgcn_mfma_f32_16x16x32_bf16(v1, x0, T1[0], 0, 0, 0);
        T1[1] = __builtin_amdgcn_mfma_f32_16x16x32_bf16(v1, x1, T1[1], 0, 0, 0);
        T1[2] = __builtin_amdgcn_mfma_f32_16x16x32_bf16(v1, x2, T1[2], 0, 0, 0);
    }
    // t1 -> shA (h1 readers drained at BAR3)
#pragma unroll
    for (int mt = 0; mt < 3; ++mt) {
        float e0 = eluf(T1[mt][0] + vb1q.x);
        float e1 = eluf(T1[mt][1] + vb1q.y);
        float e2 = eluf(T1[mt][2] + vb1q.z);
        float e3 = eluf(T1[mt][3] + vb1q.w);
        uint2 u; u.x = pack2(e0, e1); u.y = pack2(e2, e3);
        *(uint2*)(shA + (mt * 32 + prow) * 72 + wvn * 16 + quad * 4) = u;
    }
    __syncthreads();                                  // BAR4: t1 ready

    // ---- vis layer 2 + residual -> x2 (shB [32][104]) ----
    f32x4 T2[3] = {Z, Z, Z};
    {
        bf16x8 x0 = *(const bf16x8*)(shA + (0 * 32 + prow) * 72 + quad * 8);
        bf16x8 x1 = *(const bf16x8*)(shA + (1 * 32 + prow) * 72 + quad * 8);
        bf16x8 x2 = *(const bf16x8*)(shA + (2 * 32 + prow) * 72 + quad * 8);
        bf16x8 v2 = *(const bf16x8*)(V2 + (wvn * 16 + n16) * 40 + quad * 8);
        T2[0] = __builtin_amdgcn_mfma_f32_16x16x32_bf16(v2, x0, T2[0], 0, 0, 0);
        T2[1] = __builtin_amdgcn_mfma_f32_16x16x32_bf16(v2, x1, T2[1], 0, 0, 0);
        T2[2] = __builtin_amdgcn_mfma_f32_16x16x32_bf16(v2, x2, T2[2], 0, 0, 0);
    }
    // x2 -> shB (Xg readers drained at BAR2); col = view*32 + feature
#pragma unroll
    for (int mt = 0; mt < 3; ++mt) {
        float x0 = h2r[mt][0] + eluf(T2[mt][0] + vb2q.x);
        float x1 = h2r[mt][1] + eluf(T2[mt][1] + vb2q.y);
        float x2v = h2r[mt][2] + eluf(T2[mt][2] + vb2q.z);
        float x3 = h2r[mt][3] + eluf(T2[mt][3] + vb2q.w);
        uint2 u; u.x = pack2(x0, x1); u.y = pack2(x2v, x3);
        *(uint2*)(shB + prow * 104 + mt * 32 + wvn * 16 + quad * 4) = u;
    }
    __syncthreads();                                  // BAR5: x2 ready

    // ---- r1 = elu(x2 @ R1^T + rb1) ----
    f32x4 CR = Z;
#pragma unroll
    for (int ks = 0; ks < 3; ++ks) {                  // K=96
        bf16x8 xb = *(const bf16x8*)(shB + prow * 104 + ks * 32 + quad * 8);
        bf16x8 r1w = *(const bf16x8*)(R1 + (wvn * 16 + n16) * 104 + ks * 32 + quad * 8);
        CR = __builtin_amdgcn_mfma_f32_16x16x32_bf16(r1w, xb, CR, 0, 0, 0);
    }
    // r1 -> shC [32][40] (h2 readers drained at BAR4)
    {
        float e0 = eluf(CR[0] + rb1q.x);
        float e1 = eluf(CR[1] + rb1q.y);
        float e2 = eluf(CR[2] + rb1q.z);
        float e3 = eluf(CR[3] + rb1q.w);
        uint2 u; u.x = pack2(e0, e1); u.y = pack2(e2, e3);
        *(uint2*)(shC + prow * 40 + wvn * 16 + quad * 4) = u;
    }
    __syncthreads();                                  // BAR6: r1 ready

    // ---- r2 = elu(r1 @ R2^T + rb2) -> fp32 shA [32][20] ----
    f32x4 C3 = Z;
    {
        bf16x8 xb = *(const bf16x8*)(shC + prow * 40 + quad * 8);
        bf16x8 r2w = *(const bf16x8*)(R2 + n16 * 40 + quad * 8);
        C3 = __builtin_amdgcn_mfma_f32_16x16x32_bf16(r2w, xb, C3, 0, 0, 0);
    }
    // Both wvn waves compute identical C3; wvn==0 stores one float4 per lane
    // (point prow, feats quad*4..+3). t1 readers drained at BAR5.
    if (wvn == 0) {
        float4 rv;
        rv.x = eluf(C3[0] + rb2q.x);
        rv.y = eluf(C3[1] + rb2q.y);
        rv.z = eluf(C3[2] + rb2q.z);
        rv.w = eluf(C3[3] + rb2q.w);
        *(float4*)((float*)shA + prow * 20 + quad * 4) = rv;
    }
    __syncthreads();                                  // BAR7: r2 ready

    // ---- final 16 -> 3 + sigmoid (fp32), coalesced store ----
    if (tid < 96) {
        const float* r2b = (const float*)shA;
        int p = tid / 3, c = tid - p * 3;
        const float4* rr = (const float4*)(r2b + p * 20);
        const float4* w3 = (const float4*)(rw3 + c * 16);
        float4 a0 = rr[0], a1 = rr[1], a2 = rr[2], a3 = rr[3];
        float4 q0 = w3[0], q1 = w3[1], q2 = w3[2], q3 = w3[3];
        float s = rb3[c];
        s += a0.x * q0.x + a0.y * q0.y + a0.z * q0.z + a0.w * q0.w;
        s += a1.x * q1.x + a1.y * q1.y + a1.z * q1.z + a1.w * q1.w;
        s += a2.x * q2.x + a2.y * q2.y + a2.z * q2.z + a2.w * q2.w;
        s += a3.x * q3.x + a3.y * q3.y + a3.z * q3.z + a3.w * q3.w;
        out[OUT2_BASE + pbase * 3 + tid] = sigm(s);
    }
}

extern "C" void kernel_launch(void* const* d_in, const int* in_sizes, int n_in,
                              void* d_out, int out_size, void* d_ws, size_t ws_size,
                              hipStream_t stream) {
    const float* feat = (const float*)d_in[0];
    const float* bw1  = (const float*)d_in[1];
    const float* bb1  = (const float*)d_in[2];
    const float* bw2  = (const float*)d_in[3];
    const float* bb2  = (const float*)d_in[4];
    const float* vw1  = (const float*)d_in[5];
    const float* vb1  = (const float*)d_in[6];
    const float* vw2  = (const float*)d_in[7];
    const float* vb2  = (const float*)d_in[8];
    const float* rw1  = (const float*)d_in[9];
    const float* rb1  = (const float*)d_in[10];
    const float* rw2  = (const float*)d_in[11];
    const float* rb2  = (const float*)d_in[12];
    const float* rw3  = (const float*)d_in[13];
    const float* rb3  = (const float*)d_in[14];
    ushort* w  = (ushort*)d_ws;
    float* out = (float*)d_out;

    hipLaunchKernelGGL(prep_k, dim3(77), dim3(256), 0, stream,
                       bw1, bw2, vw1, vw2, rw1, rw2, w);
    hipLaunchKernelGGL(mlp_k, dim3(NBLK32), dim3(256), 0, stream,
                       feat, w, bb1, bb2, vb1, vb2, rb1, rb2, rw3, rb3, out);
}